// Round 15
// baseline (157.349 us; speedup 1.0000x reference)
//
#include <hip/hip_runtime.h>

// LNCC loss: I,J [16,1,768,768] f32 -> out [16] f32
// R15 = R13's 3-batch retention WITHOUT the launch_bounds that killed it.
// Empirical law (R6/R12/R13/R14): for 256-thread blocks, per-wave VGPR cap
// ~= 256/arg2. R13's (256,3) cap=84 vs ~160 demand -> 323MB spill. Here: NO
// launch_bounds (cap 256) -> ~160 fits, 3 waves/SIMD HW occupancy, grid 3072
// waves = exactly 12/CU. Out-rows of step s are the in-rows of step s-2, so
// three 4-row register batches A/B/C rotate statically and each step issues
// only 8 float4 loads (compulsory minimum; half of R14's 16). Masks folded
// into the batch at load (row-mask==same for in-use and out-use) -> hot path
// is pure add/fma/shfl. Shuffle-tree hsum unchanged from R12/R14.

constexpr int BATCH = 16;
constexpr int H = 768;
constexpr int W = 768;
constexpr float INV_WS = 1.0f / 81.0f;
constexpr float EPS = 3.0590232050182579e-07f;   // exp(-15)

constexpr int SEG = 16;                   // output rows per wave task
constexpr int NSEG = H / SEG;             // 48
constexpr int BANDW = 248;                // output cols per band
constexpr int NTHREADS = 256;             // 4 waves = 4 bands of one (seg,b)

__global__ void zero_acc_kernel(float* acc) {
    if (threadIdx.x < BATCH) acc[threadIdx.x] = 0.0f;
}

#define F4ADD(a, u)    { a.x += u.x; a.y += u.y; a.z += u.z; a.w += u.w; }
#define F4SUB(a, u)    { a.x -= u.x; a.y -= u.y; a.z -= u.z; a.w -= u.w; }
#define F4FMA(a, u, v) { a.x = fmaf(u.x, v.x, a.x); a.y = fmaf(u.y, v.y, a.y); \
                         a.z = fmaf(u.z, v.z, a.z); a.w = fmaf(u.w, v.w, a.w); }
#define F4FMS(a, u, v) { a.x = fmaf(u.x, -v.x, a.x); a.y = fmaf(u.y, -v.y, a.y); \
                         a.z = fmaf(u.z, -v.z, a.z); a.w = fmaf(u.w, -v.w, a.w); }

// h[e] = sum of cs cols [c0+e, c0+e+8]; output col = c0+4+e = band*248+4*lane+e
#define HSUM_SHFL(c, h)                                                   \
    {                                                                     \
        const float s3 = c.w;                                             \
        const float s2 = c.w + c.z;                                       \
        const float s1 = s2 + c.y;                                        \
        const float s0 = s1 + c.x;          /* own total */               \
        const float p1 = c.x + c.y;                                       \
        const float p2 = p1 + c.z;                                        \
        const float pn = __shfl_down(s0, 1, 64);                          \
        const float q0 = __shfl_down(c.x, 2, 64);                         \
        const float q1 = __shfl_down(p1, 2, 64);                          \
        const float q2 = __shfl_down(p2, 2, 64);                          \
        const float q3 = __shfl_down(s0, 2, 64);                          \
        h[0] = s0 + pn + q0;                                              \
        h[1] = s1 + pn + q1;                                              \
        h[2] = s2 + pn + q2;                                              \
        h[3] = s3 + pn + q3;                                              \
    }

// load 4 rows (rbase..rbase+3) PRE-MASKED: addr clamped, value scaled by
// (row in [0,H) ? fm : 0). The mask of a physical row is identical for its
// in-use and out-use, so it is applied exactly once, here.
#define LDB(NI, NJ, rbase)                                                \
    {                                                                     \
        _Pragma("unroll")                                                 \
        for (int k = 0; k < 4; ++k) {                                     \
            const int rr = (rbase) + k;                                   \
            const int rc = min(max(rr, 0), H - 1);                        \
            const float mk = (rr >= 0 && rr < H) ? fm : 0.0f;             \
            float4 ti = *(const float4*)(Ib + (size_t)rc * W + ca);       \
            float4 tj = *(const float4*)(Jb + (size_t)rc * W + ca);       \
            ti.x *= mk; ti.y *= mk; ti.z *= mk; ti.w *= mk;               \
            tj.x *= mk; tj.y *= mk; tj.z *= mk; tj.w *= mk;               \
            NI[k] = ti; NJ[k] = tj;                                       \
        }                                                                 \
    }

// one output row: in-add (pre-masked) N, hsum+math, out-sub (pre-masked) O
#define ROW1(Ni_, Nj_, Oi_, Oj_)                                          \
    {                                                                     \
        F4ADD(cs0, Ni_) F4ADD(cs1, Nj_)                                   \
        F4FMA(cs2, Ni_, Ni_) F4FMA(cs3, Nj_, Nj_) F4FMA(cs4, Ni_, Nj_)    \
        float hI[4], hJ[4], hII[4], hJJ[4], hIJ[4];                       \
        HSUM_SHFL(cs0, hI)                                                \
        HSUM_SHFL(cs1, hJ)                                                \
        HSUM_SHFL(cs2, hII)                                               \
        HSUM_SHFL(cs3, hJJ)                                               \
        HSUM_SHFL(cs4, hIJ)                                               \
        float rowsum = 0.0f;                                              \
        _Pragma("unroll")                                                 \
        for (int e = 0; e < 4; ++e) {                                     \
            const float u = -hI[e] * INV_WS;                              \
            const float cross = fmaf(u, hJ[e], hIJ[e]);                   \
            const float Ivar  = fmaf(u, hI[e], hII[e]);                   \
            const float Jvar  = fmaf(-hJ[e] * INV_WS, hJ[e], hJJ[e]);     \
            float prod = Ivar * Jvar;                                     \
            float num  = cross * cross;                                   \
            if (!(prod > EPS)) { prod = 1.0f; num = 1.0f; }               \
            float inv_;                                                   \
            asm("v_rcp_f32 %0, %1" : "=v"(inv_) : "v"(prod + EPS));       \
            rowsum = fmaf(num, inv_, rowsum);                             \
        }                                                                 \
        accum += live ? rowsum : 0.0f;                                    \
        F4SUB(cs0, Oi_) F4SUB(cs1, Oj_)                                   \
        F4FMS(cs2, Oi_, Oi_) F4FMS(cs3, Oj_, Oj_) F4FMS(cs4, Oi_, Oj_)    \
    }

// 4 rows: in-batch N (rows r+4..r+7), out-batch O (rows r-4..r-1)
#define ROW4(NI, NJ, OI, OJ)                                              \
    ROW1(NI[0], NJ[0], OI[0], OJ[0])                                      \
    ROW1(NI[1], NJ[1], OI[1], OJ[1])                                      \
    ROW1(NI[2], NJ[2], OI[2], OJ[2])                                      \
    ROW1(NI[3], NJ[3], OI[3], OJ[3])

__global__ void lncc_r3(const float* __restrict__ gI, const float* __restrict__ gJ,
                        float* __restrict__ acc)
{
    __shared__ float wsum[4];

    const int lane = threadIdx.x & 63;
    const int band = threadIdx.x >> 6;                   // 0..3
    const int r0   = blockIdx.x * SEG;
    const int b    = blockIdx.y;
    const int c0   = band * BANDW - 4 + 4 * lane;        // own cs base col
    const float fm = (c0 >= 0 && c0 + 3 < W) ? 1.0f : 0.0f;
    const int ca   = min(max(c0, 0), W - 4);             // 16B-aligned clamp
    const bool live = (lane <= 61) && (band * BANDW + 4 * lane + 3 < W);

    const float* __restrict__ Ib = gI + (size_t)b * (H * W);
    const float* __restrict__ Jb = gJ + (size_t)b * (H * W);

    float4 cs0 = {0,0,0,0}, cs1 = {0,0,0,0}, cs2 = {0,0,0,0},
           cs3 = {0,0,0,0}, cs4 = {0,0,0,0};

    float4 Ai[4], Aj[4], Bi[4], Bj[4], Ci[4], Cj[4];

    // ---- warm-up: A = rows r0-4..r0-1, B = rows r0..r0+3 (both pre-masked)
    LDB(Ai, Aj, r0 - 4)
    LDB(Bi, Bj, r0)
    #pragma unroll
    for (int k = 0; k < 4; ++k) {
        F4ADD(cs0, Ai[k]) F4ADD(cs1, Aj[k])
        F4FMA(cs2, Ai[k], Ai[k]) F4FMA(cs3, Aj[k], Aj[k]) F4FMA(cs4, Ai[k], Aj[k])
    }
    #pragma unroll
    for (int k = 0; k < 4; ++k) {
        F4ADD(cs0, Bi[k]) F4ADD(cs1, Bj[k])
        F4FMA(cs2, Bi[k], Bi[k]) F4FMA(cs3, Bj[k], Bj[k]) F4FMA(cs4, Bi[k], Bj[k])
    }

    float accum = 0.0f;

    // ---- 4 statically-rotated steps of 4 rows (SEG = 16), 8 loads/step ----
    LDB(Ci, Cj, r0 + 4)   ROW4(Ci, Cj, Ai, Aj)   // rows r0..3:    in=C, out=A
    LDB(Ai, Aj, r0 + 8)   ROW4(Ai, Aj, Bi, Bj)   // rows r0+4..7:  in=A, out=B
    LDB(Bi, Bj, r0 + 12)  ROW4(Bi, Bj, Ci, Cj)   // rows r0+8..11: in=B, out=C
    LDB(Ci, Cj, r0 + 16)  ROW4(Ci, Cj, Ai, Aj)   // rows r0+12..15: in=C, out=A

    // ---- wave reduce -> block reduce -> one atomic per block ----
    #pragma unroll
    for (int off = 32; off > 0; off >>= 1)
        accum += __shfl_xor(accum, off, 64);
    if (lane == 0) wsum[band] = accum;
    __syncthreads();
    if (threadIdx.x == 0)
        atomicAdd(&acc[b], wsum[0] + wsum[1] + wsum[2] + wsum[3]);
}

__global__ void finalize_kernel(const float* __restrict__ acc, float* __restrict__ out) {
    if (threadIdx.x < BATCH)
        out[threadIdx.x] = 1.0f - acc[threadIdx.x] * (1.0f / (float)(H * W));
}

extern "C" void kernel_launch(void* const* d_in, const int* in_sizes, int n_in,
                              void* d_out, int out_size, void* d_ws, size_t ws_size,
                              hipStream_t stream) {
    const float* I = (const float*)d_in[0];
    const float* J = (const float*)d_in[1];
    float* out = (float*)d_out;
    float* acc = (float*)d_ws;

    zero_acc_kernel<<<1, 64, 0, stream>>>(acc);

    dim3 grid(NSEG, BATCH);   // 48 x 16 = 768 blocks, 3072 waves = 12/CU
    lncc_r3<<<grid, NTHREADS, 0, stream>>>(I, J, acc);

    finalize_kernel<<<1, 64, 0, stream>>>(acc, out);
}

// Round 16
// 61.611 us; speedup vs baseline: 2.5539x; 2.5539x over previous
//
#include <hip/hip_runtime.h>

// LNCC loss: I,J [16,1,768,768] f32 -> out [16] f32
// R16 = R15's 3-batch retention with the VGPR cap finally set right.
// Empirical hipcc law (R6/R12/R13/R14/R15): for 256-thread blocks the
// per-wave VGPR cap ~= 256/arg2, and with NO launch_bounds hipcc defaults
// to ~64 (R15: 64 VGPR, 284MB spill). (256,1) -> cap 256; ~160-reg demand
// fits; HW occupancy 3 waves/SIMD; grid 3072 waves = exactly 12/CU.
// Out-rows of step s are the in-rows of step s-2: three 4-row register
// batches A/B/C rotate statically; each step issues 8 float4 loads
// (compulsory minimum, 44% fewer per row than R14). Masks folded into the
// batch at load. First step's LDB hoisted above the warm-up accumulate so
// its latency hides under ~800cy of compute.

constexpr int BATCH = 16;
constexpr int H = 768;
constexpr int W = 768;
constexpr float INV_WS = 1.0f / 81.0f;
constexpr float EPS = 3.0590232050182579e-07f;   // exp(-15)

constexpr int SEG = 16;                   // output rows per wave task
constexpr int NSEG = H / SEG;             // 48
constexpr int BANDW = 248;                // output cols per band
constexpr int NTHREADS = 256;             // 4 waves = 4 bands of one (seg,b)

__global__ void zero_acc_kernel(float* acc) {
    if (threadIdx.x < BATCH) acc[threadIdx.x] = 0.0f;
}

#define F4ADD(a, u)    { a.x += u.x; a.y += u.y; a.z += u.z; a.w += u.w; }
#define F4SUB(a, u)    { a.x -= u.x; a.y -= u.y; a.z -= u.z; a.w -= u.w; }
#define F4FMA(a, u, v) { a.x = fmaf(u.x, v.x, a.x); a.y = fmaf(u.y, v.y, a.y); \
                         a.z = fmaf(u.z, v.z, a.z); a.w = fmaf(u.w, v.w, a.w); }
#define F4FMS(a, u, v) { a.x = fmaf(u.x, -v.x, a.x); a.y = fmaf(u.y, -v.y, a.y); \
                         a.z = fmaf(u.z, -v.z, a.z); a.w = fmaf(u.w, -v.w, a.w); }

// h[e] = sum of cs cols [c0+e, c0+e+8]; output col = c0+4+e = band*248+4*lane+e
#define HSUM_SHFL(c, h)                                                   \
    {                                                                     \
        const float s3 = c.w;                                             \
        const float s2 = c.w + c.z;                                       \
        const float s1 = s2 + c.y;                                        \
        const float s0 = s1 + c.x;          /* own total */               \
        const float p1 = c.x + c.y;                                       \
        const float p2 = p1 + c.z;                                        \
        const float pn = __shfl_down(s0, 1, 64);                          \
        const float q0 = __shfl_down(c.x, 2, 64);                         \
        const float q1 = __shfl_down(p1, 2, 64);                          \
        const float q2 = __shfl_down(p2, 2, 64);                          \
        const float q3 = __shfl_down(s0, 2, 64);                          \
        h[0] = s0 + pn + q0;                                              \
        h[1] = s1 + pn + q1;                                              \
        h[2] = s2 + pn + q2;                                              \
        h[3] = s3 + pn + q3;                                              \
    }

// load 4 rows (rbase..rbase+3) PRE-MASKED: addr clamped, value scaled by
// (row in [0,H) ? fm : 0). A physical row's mask is identical for its
// in-use and out-use, so it is applied exactly once, here.
#define LDB(NI, NJ, rbase)                                                \
    {                                                                     \
        _Pragma("unroll")                                                 \
        for (int k = 0; k < 4; ++k) {                                     \
            const int rr = (rbase) + k;                                   \
            const int rc = min(max(rr, 0), H - 1);                        \
            const float mk = (rr >= 0 && rr < H) ? fm : 0.0f;             \
            float4 ti = *(const float4*)(Ib + (size_t)rc * W + ca);       \
            float4 tj = *(const float4*)(Jb + (size_t)rc * W + ca);       \
            ti.x *= mk; ti.y *= mk; ti.z *= mk; ti.w *= mk;               \
            tj.x *= mk; tj.y *= mk; tj.z *= mk; tj.w *= mk;               \
            NI[k] = ti; NJ[k] = tj;                                       \
        }                                                                 \
    }

// one output row: in-add (pre-masked) N, hsum+math, out-sub (pre-masked) O
#define ROW1(Ni_, Nj_, Oi_, Oj_)                                          \
    {                                                                     \
        F4ADD(cs0, Ni_) F4ADD(cs1, Nj_)                                   \
        F4FMA(cs2, Ni_, Ni_) F4FMA(cs3, Nj_, Nj_) F4FMA(cs4, Ni_, Nj_)    \
        float hI[4], hJ[4], hII[4], hJJ[4], hIJ[4];                       \
        HSUM_SHFL(cs0, hI)                                                \
        HSUM_SHFL(cs1, hJ)                                                \
        HSUM_SHFL(cs2, hII)                                               \
        HSUM_SHFL(cs3, hJJ)                                               \
        HSUM_SHFL(cs4, hIJ)                                               \
        float rowsum = 0.0f;                                              \
        _Pragma("unroll")                                                 \
        for (int e = 0; e < 4; ++e) {                                     \
            const float u = -hI[e] * INV_WS;                              \
            const float cross = fmaf(u, hJ[e], hIJ[e]);                   \
            const float Ivar  = fmaf(u, hI[e], hII[e]);                   \
            const float Jvar  = fmaf(-hJ[e] * INV_WS, hJ[e], hJJ[e]);     \
            float prod = Ivar * Jvar;                                     \
            float num  = cross * cross;                                   \
            if (!(prod > EPS)) { prod = 1.0f; num = 1.0f; }               \
            float inv_;                                                   \
            asm("v_rcp_f32 %0, %1" : "=v"(inv_) : "v"(prod + EPS));       \
            rowsum = fmaf(num, inv_, rowsum);                             \
        }                                                                 \
        accum += live ? rowsum : 0.0f;                                    \
        F4SUB(cs0, Oi_) F4SUB(cs1, Oj_)                                   \
        F4FMS(cs2, Oi_, Oi_) F4FMS(cs3, Oj_, Oj_) F4FMS(cs4, Oi_, Oj_)    \
    }

// 4 rows: in-batch N (rows r+4..r+7), out-batch O (rows r-4..r-1)
#define ROW4(NI, NJ, OI, OJ)                                              \
    ROW1(NI[0], NJ[0], OI[0], OJ[0])                                      \
    ROW1(NI[1], NJ[1], OI[1], OJ[1])                                      \
    ROW1(NI[2], NJ[2], OI[2], OJ[2])                                      \
    ROW1(NI[3], NJ[3], OI[3], OJ[3])

__launch_bounds__(NTHREADS, 1)
__global__ void lncc_r3(const float* __restrict__ gI, const float* __restrict__ gJ,
                        float* __restrict__ acc)
{
    __shared__ float wsum[4];

    const int lane = threadIdx.x & 63;
    const int band = threadIdx.x >> 6;                   // 0..3
    const int r0   = blockIdx.x * SEG;
    const int b    = blockIdx.y;
    const int c0   = band * BANDW - 4 + 4 * lane;        // own cs base col
    const float fm = (c0 >= 0 && c0 + 3 < W) ? 1.0f : 0.0f;
    const int ca   = min(max(c0, 0), W - 4);             // 16B-aligned clamp
    const bool live = (lane <= 61) && (band * BANDW + 4 * lane + 3 < W);

    const float* __restrict__ Ib = gI + (size_t)b * (H * W);
    const float* __restrict__ Jb = gJ + (size_t)b * (H * W);

    float4 cs0 = {0,0,0,0}, cs1 = {0,0,0,0}, cs2 = {0,0,0,0},
           cs3 = {0,0,0,0}, cs4 = {0,0,0,0};

    float4 Ai[4], Aj[4], Bi[4], Bj[4], Ci[4], Cj[4];

    // ---- warm-up loads: A = rows r0-4..r0-1, B = rows r0..r0+3 (pre-masked)
    LDB(Ai, Aj, r0 - 4)
    LDB(Bi, Bj, r0)
    // hoisted: step-1's in-batch C (rows r0+4..r0+7) — lands under warm-up VALU
    LDB(Ci, Cj, r0 + 4)

    // ---- warm-up accumulate: 8 rows of colsum adds (~800 cy) ----
    #pragma unroll
    for (int k = 0; k < 4; ++k) {
        F4ADD(cs0, Ai[k]) F4ADD(cs1, Aj[k])
        F4FMA(cs2, Ai[k], Ai[k]) F4FMA(cs3, Aj[k], Aj[k]) F4FMA(cs4, Ai[k], Aj[k])
    }
    #pragma unroll
    for (int k = 0; k < 4; ++k) {
        F4ADD(cs0, Bi[k]) F4ADD(cs1, Bj[k])
        F4FMA(cs2, Bi[k], Bi[k]) F4FMA(cs3, Bj[k], Bj[k]) F4FMA(cs4, Bi[k], Bj[k])
    }

    float accum = 0.0f;

    // ---- 4 statically-rotated steps of 4 rows (SEG = 16), 8 loads/step ----
    /* step 1: C pre-loaded */ ROW4(Ci, Cj, Ai, Aj)   // rows r0..3:     in=C, out=A
    LDB(Ai, Aj, r0 + 8)        ROW4(Ai, Aj, Bi, Bj)   // rows r0+4..7:   in=A, out=B
    LDB(Bi, Bj, r0 + 12)       ROW4(Bi, Bj, Ci, Cj)   // rows r0+8..11:  in=B, out=C
    LDB(Ci, Cj, r0 + 16)       ROW4(Ci, Cj, Ai, Aj)   // rows r0+12..15: in=C, out=A

    // ---- wave reduce -> block reduce -> one atomic per block ----
    #pragma unroll
    for (int off = 32; off > 0; off >>= 1)
        accum += __shfl_xor(accum, off, 64);
    if (lane == 0) wsum[band] = accum;
    __syncthreads();
    if (threadIdx.x == 0)
        atomicAdd(&acc[b], wsum[0] + wsum[1] + wsum[2] + wsum[3]);
}

__global__ void finalize_kernel(const float* __restrict__ acc, float* __restrict__ out) {
    if (threadIdx.x < BATCH)
        out[threadIdx.x] = 1.0f - acc[threadIdx.x] * (1.0f / (float)(H * W));
}

extern "C" void kernel_launch(void* const* d_in, const int* in_sizes, int n_in,
                              void* d_out, int out_size, void* d_ws, size_t ws_size,
                              hipStream_t stream) {
    const float* I = (const float*)d_in[0];
    const float* J = (const float*)d_in[1];
    float* out = (float*)d_out;
    float* acc = (float*)d_ws;

    zero_acc_kernel<<<1, 64, 0, stream>>>(acc);

    dim3 grid(NSEG, BATCH);   // 48 x 16 = 768 blocks, 3072 waves = 12/CU
    lncc_r3<<<grid, NTHREADS, 0, stream>>>(I, J, acc);

    finalize_kernel<<<1, 64, 0, stream>>>(acc, out);
}

// Round 17
// 43.220 us; speedup vs baseline: 3.6406x; 1.4255x over previous
//
#include <hip/hip_runtime.h>

// LNCC loss: I,J [16,1,768,768] f32 -> out [16] f32
// R17 = R14 (best 39.1us, 88 VGPR, 16 waves/CU) + deep software pipeline.
// Occupancy law (m69 + R14/R16): waves/SIMD steps at VGPR {64,128,256} ->
// {8,4,2}; 128 is a cliff (R16: 148 VGPR -> 8 waves/CU -> 64us). Stay <=128.
// Harness fills evict L3 between replays -> in-rows are HBM-cold (~900cy).
// Pipeline: 2-row chunks; in-loads issued 2 chunks (~1400cy compute) ahead;
// out-loads (L3-hot, same-kernel refetch) 1 chunk ahead, ping-pong buffers.
// Masks folded at load (each loaded row consumed exactly once).
// Pinned regs: 3 IN bufs (48) + 2 OUT bufs (32) + cs (20) ~= 100.

constexpr int BATCH = 16;
constexpr int H = 768;
constexpr int W = 768;
constexpr float INV_WS = 1.0f / 81.0f;
constexpr float EPS = 3.0590232050182579e-07f;   // exp(-15)

constexpr int SEG = 12;                   // output rows per wave task
constexpr int NSEG = H / SEG;             // 64
constexpr int BANDW = 248;                // output cols per band
constexpr int NTHREADS = 256;             // 4 waves = 4 bands of one (seg,b)

__global__ void zero_acc_kernel(float* acc) {
    if (threadIdx.x < BATCH) acc[threadIdx.x] = 0.0f;
}

#define F4ADD(a, u)    { a.x += u.x; a.y += u.y; a.z += u.z; a.w += u.w; }
#define F4SUB(a, u)    { a.x -= u.x; a.y -= u.y; a.z -= u.z; a.w -= u.w; }
#define F4FMA(a, u, v) { a.x = fmaf(u.x, v.x, a.x); a.y = fmaf(u.y, v.y, a.y); \
                         a.z = fmaf(u.z, v.z, a.z); a.w = fmaf(u.w, v.w, a.w); }
#define F4FMS(a, u, v) { a.x = fmaf(u.x, -v.x, a.x); a.y = fmaf(u.y, -v.y, a.y); \
                         a.z = fmaf(u.z, -v.z, a.z); a.w = fmaf(u.w, -v.w, a.w); }

// h[e] = sum of cs cols [c0+e, c0+e+8]; output col = c0+4+e = band*248+4*lane+e
#define HSUM_SHFL(c, h)                                                   \
    {                                                                     \
        const float s3 = c.w;                                             \
        const float s2 = c.w + c.z;                                       \
        const float s1 = s2 + c.y;                                        \
        const float s0 = s1 + c.x;          /* own total */               \
        const float p1 = c.x + c.y;                                       \
        const float p2 = p1 + c.z;                                        \
        const float pn = __shfl_down(s0, 1, 64);                          \
        const float q0 = __shfl_down(c.x, 2, 64);                         \
        const float q1 = __shfl_down(p1, 2, 64);                          \
        const float q2 = __shfl_down(p2, 2, 64);                          \
        const float q3 = __shfl_down(s0, 2, 64);                          \
        h[0] = s0 + pn + q0;                                              \
        h[1] = s1 + pn + q1;                                              \
        h[2] = s2 + pn + q2;                                              \
        h[3] = s3 + pn + q3;                                              \
    }

// load 2 rows (rbase, rbase+1) PRE-MASKED: addr clamped, value scaled by
// (row in [0,H) ? fm : 0); each loaded row is consumed exactly once.
#define LD2(NI, NJ, rbase)                                                \
    {                                                                     \
        _Pragma("unroll")                                                 \
        for (int k = 0; k < 2; ++k) {                                     \
            const int rr = (rbase) + k;                                   \
            const int rc = min(max(rr, 0), H - 1);                        \
            const float mk = (rr >= 0 && rr < H) ? fm : 0.0f;             \
            float4 ti = *(const float4*)(Ib + (size_t)rc * W + ca);       \
            float4 tj = *(const float4*)(Jb + (size_t)rc * W + ca);       \
            ti.x *= mk; ti.y *= mk; ti.z *= mk; ti.w *= mk;               \
            tj.x *= mk; tj.y *= mk; tj.z *= mk; tj.w *= mk;               \
            NI[k] = ti; NJ[k] = tj;                                       \
        }                                                                 \
    }

// compute 2 output rows from pre-masked in-batch (VI,VJ) and out-batch (OI,OJ)
#define CHUNK(VI, VJ, OI, OJ)                                             \
    _Pragma("unroll")                                                     \
    for (int k = 0; k < 2; ++k) {                                         \
        F4ADD(cs0, VI[k]) F4ADD(cs1, VJ[k])                               \
        F4FMA(cs2, VI[k], VI[k]) F4FMA(cs3, VJ[k], VJ[k])                 \
        F4FMA(cs4, VI[k], VJ[k])                                          \
        float hI[4], hJ[4], hII[4], hJJ[4], hIJ[4];                       \
        HSUM_SHFL(cs0, hI)                                                \
        HSUM_SHFL(cs1, hJ)                                                \
        HSUM_SHFL(cs2, hII)                                               \
        HSUM_SHFL(cs3, hJJ)                                               \
        HSUM_SHFL(cs4, hIJ)                                               \
        float rowsum = 0.0f;                                              \
        _Pragma("unroll")                                                 \
        for (int e = 0; e < 4; ++e) {                                     \
            const float u = -hI[e] * INV_WS;                              \
            const float cross = fmaf(u, hJ[e], hIJ[e]);                   \
            const float Ivar  = fmaf(u, hI[e], hII[e]);                   \
            const float Jvar  = fmaf(-hJ[e] * INV_WS, hJ[e], hJJ[e]);     \
            float prod = Ivar * Jvar;                                     \
            float num  = cross * cross;                                   \
            if (!(prod > EPS)) { prod = 1.0f; num = 1.0f; }               \
            float inv_;                                                   \
            asm("v_rcp_f32 %0, %1" : "=v"(inv_) : "v"(prod + EPS));       \
            rowsum = fmaf(num, inv_, rowsum);                             \
        }                                                                 \
        accum += live ? rowsum : 0.0f;                                    \
        F4SUB(cs0, OI[k]) F4SUB(cs1, OJ[k])                               \
        F4FMS(cs2, OI[k], OI[k]) F4FMS(cs3, OJ[k], OJ[k])                 \
        F4FMS(cs4, OI[k], OJ[k])                                          \
    }

__launch_bounds__(NTHREADS, 2)
__global__ void lncc_pipe(const float* __restrict__ gI, const float* __restrict__ gJ,
                          float* __restrict__ acc)
{
    __shared__ float wsum[4];

    const int lane = threadIdx.x & 63;
    const int band = threadIdx.x >> 6;                   // 0..3
    const int r0   = blockIdx.x * SEG;
    const int b    = blockIdx.y;
    const int c0   = band * BANDW - 4 + 4 * lane;        // own cs base col
    const float fm = (c0 >= 0 && c0 + 3 < W) ? 1.0f : 0.0f;
    const int ca   = min(max(c0, 0), W - 4);             // 16B-aligned clamp
    const bool live = (lane <= 61) && (band * BANDW + 4 * lane + 3 < W);

    const float* __restrict__ Ib = gI + (size_t)b * (H * W);
    const float* __restrict__ Jb = gJ + (size_t)b * (H * W);

    float4 cs0 = {0,0,0,0}, cs1 = {0,0,0,0}, cs2 = {0,0,0,0},
           cs3 = {0,0,0,0}, cs4 = {0,0,0,0};

    // ---- warm-up: 4 pre-masked 2-row chunks (rows r0-4 .. r0+3) ----
    float4 W0i[2], W0j[2], W1i[2], W1j[2], W2i[2], W2j[2], W3i[2], W3j[2];
    LD2(W0i, W0j, r0 - 4)
    LD2(W1i, W1j, r0 - 2)
    LD2(W2i, W2j, r0)
    LD2(W3i, W3j, r0 + 2)

    // ---- pipeline preload: in-chunks 0,1 (depth 2) + out-chunk 0 ----
    float4 I0i[2], I0j[2], I1i[2], I1j[2], I2i[2], I2j[2];
    float4 I3i[2], I3j[2], I4i[2], I4j[2], I5i[2], I5j[2];
    float4 OAi[2], OAj[2], OBi[2], OBj[2];
    LD2(I0i, I0j, r0 + 4)
    LD2(I1i, I1j, r0 + 6)
    LD2(OAi, OAj, r0 - 4)

    // warm-up accumulate (~700 cy) covers the preload latency
#define WACC(WI, WJ)                                                      \
    _Pragma("unroll")                                                     \
    for (int k = 0; k < 2; ++k) {                                         \
        F4ADD(cs0, WI[k]) F4ADD(cs1, WJ[k])                               \
        F4FMA(cs2, WI[k], WI[k]) F4FMA(cs3, WJ[k], WJ[k])                 \
        F4FMA(cs4, WI[k], WJ[k])                                          \
    }
    WACC(W0i, W0j) WACC(W1i, W1j) WACC(W2i, W2j) WACC(W3i, W3j)
#undef WACC

    float accum = 0.0f;

    // ---- 6 pipelined chunks of 2 rows (SEG = 12) ----
    // chunk c: rows r0+2c, +1; in-rows r0+2c+4 (issued 2 chunks ahead);
    // out-rows r0+2c-4 (issued 1 chunk ahead, ping-pong OA/OB).
    LD2(I2i, I2j, r0 + 8)   LD2(OBi, OBj, r0 - 2)   CHUNK(I0i, I0j, OAi, OAj)
    LD2(I3i, I3j, r0 + 10)  LD2(OAi, OAj, r0)       CHUNK(I1i, I1j, OBi, OBj)
    LD2(I4i, I4j, r0 + 12)  LD2(OBi, OBj, r0 + 2)   CHUNK(I2i, I2j, OAi, OAj)
    LD2(I5i, I5j, r0 + 14)  LD2(OAi, OAj, r0 + 4)   CHUNK(I3i, I3j, OBi, OBj)
                            LD2(OBi, OBj, r0 + 6)   CHUNK(I4i, I4j, OAi, OAj)
                                                    CHUNK(I5i, I5j, OBi, OBj)

    // ---- wave reduce -> block reduce -> one atomic per block ----
    #pragma unroll
    for (int off = 32; off > 0; off >>= 1)
        accum += __shfl_xor(accum, off, 64);
    if (lane == 0) wsum[band] = accum;
    __syncthreads();
    if (threadIdx.x == 0)
        atomicAdd(&acc[b], wsum[0] + wsum[1] + wsum[2] + wsum[3]);
}

__global__ void finalize_kernel(const float* __restrict__ acc, float* __restrict__ out) {
    if (threadIdx.x < BATCH)
        out[threadIdx.x] = 1.0f - acc[threadIdx.x] * (1.0f / (float)(H * W));
}

extern "C" void kernel_launch(void* const* d_in, const int* in_sizes, int n_in,
                              void* d_out, int out_size, void* d_ws, size_t ws_size,
                              hipStream_t stream) {
    const float* I = (const float*)d_in[0];
    const float* J = (const float*)d_in[1];
    float* out = (float*)d_out;
    float* acc = (float*)d_ws;

    zero_acc_kernel<<<1, 64, 0, stream>>>(acc);

    dim3 grid(NSEG, BATCH);   // 64 x 16 = 1024 blocks = 4/CU, 16 waves/CU
    lncc_pipe<<<grid, NTHREADS, 0, stream>>>(I, J, acc);

    finalize_kernel<<<1, 64, 0, stream>>>(acc, out);
}